// Round 1
// baseline (277.360 us; speedup 1.0000x reference)
//
#include <hip/hip_runtime.h>
#include <hip/hip_fp16.h>
#include <math.h>

// ---------------------------------------------------------------------------
// GCN 2-layer + two heads, fp32 in/out, MI355X.
//   CSR build via 2-level counting sort (atomic-light) ->
//   GEMMs via split-bf16 MFMA -> CSR gather aggregate over fp16 features.
//   R6: agg = one node per 16-lane group (4x chain parallelism, no cross-lane
//   reduce, predicated gathers); partition BKE 4096->2048 (2x occupancy).
// ---------------------------------------------------------------------------

#define DFEAT 128
#define BSH 8            // bucket = dst >> 8 (256 nodes/bucket)
#define BKE 2048         // edges per partition block

using short8  = __attribute__((ext_vector_type(8))) short;
using floatx4 = __attribute__((ext_vector_type(4))) float;

__device__ __forceinline__ unsigned short f2bf_rne(float x) {
    unsigned u = __float_as_uint(x);
    unsigned r = u + 0x7FFFu + ((u >> 16) & 1u);
    return (unsigned short)(r >> 16);
}

// ------------------- Pass A: coarse bucket histogram ------------------------
__global__ __launch_bounds__(256) void bucket_hist_k(const int* __restrict__ dst,
                                                     int* __restrict__ bucket_cnt,
                                                     int E, int nbuk) {
    __shared__ int h[256];
    int tid = threadIdx.x;
    h[tid] = 0;
    __syncthreads();
    int nb = gridDim.x;
    int len = ((E + nb - 1) / nb + 3) & ~3;
    int e0 = blockIdx.x * len;
    int e1 = E < e0 + len ? E : e0 + len;
    int m = e1 - e0; if (m < 0) m = 0;
    int e1a = e0 + (m & ~3);
    for (int e = e0 + tid * 4; e < e1a; e += 1024) {
        int4 d4 = *(const int4*)(dst + e);
        atomicAdd(&h[d4.x >> BSH], 1);
        atomicAdd(&h[d4.y >> BSH], 1);
        atomicAdd(&h[d4.z >> BSH], 1);
        atomicAdd(&h[d4.w >> BSH], 1);
    }
    for (int e = e1a + tid; e < e1; e += 256) atomicAdd(&h[dst[e] >> BSH], 1);
    __syncthreads();
    if (tid < nbuk && h[tid]) atomicAdd(&bucket_cnt[tid], h[tid]);
}

// ------------------- scan bucket counts -> offsets + cursor ----------------
__global__ __launch_bounds__(256) void scan_buckets_k(const int* __restrict__ cnt,
                                                      int* __restrict__ off,
                                                      int* __restrict__ cursor,
                                                      int nbuk, int E) {
    __shared__ int s[256];
    int tid = threadIdx.x;
    int v = (tid < nbuk) ? cnt[tid] : 0;
    s[tid] = v;
    __syncthreads();
    int x = v;
    for (int o = 1; o < 256; o <<= 1) {
        int y = (tid >= o) ? s[tid - o] : 0;
        __syncthreads();
        x += y;
        s[tid] = x;
        __syncthreads();
    }
    if (tid < nbuk) { off[tid] = x - v; cursor[tid] = x - v; }
    if (tid == 0) off[nbuk] = E;
}

// ------------------- Pass B: partition edges into buckets -------------------
// 391 blocks x 2048 edges. LDS rank atomics + one global reservation atomic
// per (block,bucket). Writes packed (dst<<16 | src) in ~10-entry runs.
__global__ __launch_bounds__(256) void partition_k(const int* __restrict__ src,
                                                   const int* __restrict__ dst,
                                                   int* __restrict__ cursor,
                                                   unsigned* __restrict__ pk_out,
                                                   int E, int nbuk) {
    __shared__ int h[256];
    __shared__ int base[256];
    int tid = threadIdx.x;
    h[tid] = 0;
    __syncthreads();
    int e0 = blockIdx.x * BKE;

    unsigned pk[8];
    unsigned short rk[8];
    unsigned char bk[8];
    int m = 0;
#pragma unroll
    for (int it = 0; it < 2; ++it) {
        int e = e0 + it * 1024 + tid * 4;
        if (e + 3 < E) {
            int4 d4 = *(const int4*)(dst + e);
            int4 s4 = *(const int4*)(src + e);
            int dd[4] = {d4.x, d4.y, d4.z, d4.w};
            int ss[4] = {s4.x, s4.y, s4.z, s4.w};
#pragma unroll
            for (int k = 0; k < 4; ++k) {
                int b = dd[k] >> BSH;
                pk[m] = ((unsigned)dd[k] << 16) | (unsigned)ss[k];
                rk[m] = (unsigned short)atomicAdd(&h[b], 1);
                bk[m] = (unsigned char)b;
                ++m;
            }
        } else {
            for (int k = 0; k < 4; ++k) {
                if (e + k < E) {
                    int d = dst[e + k], sv = src[e + k];
                    int b = d >> BSH;
                    pk[m] = ((unsigned)d << 16) | (unsigned)sv;
                    rk[m] = (unsigned short)atomicAdd(&h[b], 1);
                    bk[m] = (unsigned char)b;
                    ++m;
                }
            }
        }
    }
    __syncthreads();
    if (tid < nbuk && h[tid]) base[tid] = atomicAdd(&cursor[tid], h[tid]);
    __syncthreads();
    for (int j = 0; j < m; ++j)
        pk_out[base[bk[j]] + (int)rk[j]] = pk[j];
}

// ------------------- Pass C: per-bucket exact CSR ---------------------------
// One block per bucket. LDS histogram of 256 local nodes + LDS scan ->
// row_ptr, dinv, and col_idx (ushort) into a block-exclusive slab.
__global__ __launch_bounds__(256) void build_csr_k(const unsigned* __restrict__ pk_arr,
                                                   const int* __restrict__ off,
                                                   int* __restrict__ row_ptr,
                                                   unsigned short* __restrict__ col_idx,
                                                   float* __restrict__ dinv,
                                                   int N, int E) {
    __shared__ int hcnt[256];
    __shared__ int esc[256];
    int b = blockIdx.x, tid = threadIdx.x;
    hcnt[tid] = 0;
    __syncthreads();
    int s0 = off[b], s1 = off[b + 1];
    int cnt = s1 - s0;

    unsigned p[20];
    unsigned short r[20];
    int m = 0;
    for (int i = tid; i < cnt; i += 256) {
        unsigned pp = pk_arr[s0 + i];
        int d = (pp >> 16) & 255;
        r[m] = (unsigned short)atomicAdd(&hcnt[d], 1);
        p[m] = pp;
        ++m;
    }
    __syncthreads();

    int v = hcnt[tid];
    esc[tid] = v;
    __syncthreads();
    int x = v;
    for (int o = 1; o < 256; o <<= 1) {
        int y = (tid >= o) ? esc[tid - o] : 0;
        __syncthreads();
        x += y;
        esc[tid] = x;
        __syncthreads();
    }
    int excl = x - v;
    __syncthreads();
    esc[tid] = excl;
    __syncthreads();

    int node = (b << BSH) + tid;
    if (node < N) {
        row_ptr[node] = s0 + excl;
        dinv[node] = rsqrtf((float)(v + 1));   // +1 self loop
    }
    if (node == N) row_ptr[N] = E;

    for (int j = 0; j < m; ++j) {
        int d = (p[j] >> 16) & 255;
        col_idx[s0 + esc[d] + (int)r[j]] = (unsigned short)(p[j] & 0xFFFFu);
    }
}

// ------------------------- W pre-split to MFMA frags ------------------------
__global__ __launch_bounds__(256) void prep_w4_k(const float* __restrict__ W0,
                                                 const float* __restrict__ W1,
                                                 const float* __restrict__ W2,
                                                 const float* __restrict__ W3,
                                                 short* __restrict__ hi_all,
                                                 short* __restrict__ lo_all) {
    int b = blockIdx.x >> 6;
    const float* W = (b == 0) ? W0 : (b == 1) ? W1 : (b == 2) ? W2 : W3;
    short* hi = hi_all + (size_t)b * 16384;
    short* lo = lo_all + (size_t)b * 16384;
    int i = (blockIdx.x & 63) * 256 + threadIdx.x;
    int j = i & 7;
    int lane = (i >> 3) & 63;
    int ts = i >> 9;
    int s = ts & 3, t = ts >> 2;
    int k = s * 32 + (lane >> 4) * 8 + j;
    int n = t * 16 + (lane & 15);
    float x = W[k * 128 + n];
    unsigned short h = f2bf_rne(x);
    float res = x - __uint_as_float(((unsigned)h) << 16);
    hi[i] = (short)h;
    lo[i] = (short)f2bf_rne(res);
}

// ----------------------- GEMM via split-bf16 MFMA ---------------------------
template <typename InT, typename OutT, bool SCALE, bool BIAS, bool RELU>
__device__ __forceinline__ void gemm_core(const InT* __restrict__ X,
                                          const short* __restrict__ Whi,
                                          const short* __restrict__ Wlo,
                                          const float* __restrict__ scale,
                                          const float* __restrict__ bias,
                                          OutT* __restrict__ Y, int M, int blk) {
    __shared__ short WhiS[16384];
    __shared__ short WloS[16384];
    const int tid = threadIdx.x;

#pragma unroll
    for (int j = 0; j < 8; ++j)
        ((float4*)WhiS)[tid + j * 256] = ((const float4*)Whi)[tid + j * 256];
#pragma unroll
    for (int j = 0; j < 8; ++j)
        ((float4*)WloS)[tid + j * 256] = ((const float4*)Wlo)[tid + j * 256];

    const int wave = tid >> 6, lane = tid & 63;
    const int quad = lane >> 4, l16 = lane & 15;
    const int m0 = blk * 128 + wave * 32;

    short8 Ahi[2][4], Alo[2][4];
#pragma unroll
    for (int r = 0; r < 2; ++r) {
        int row = m0 + r * 16 + l16;
        row = row < M ? row : (M - 1);
        const InT* xr = X + (size_t)row * 128 + quad * 8;
#pragma unroll
        for (int s = 0; s < 4; ++s) {
            float v[8];
            if constexpr (sizeof(InT) == 4) {
                float4 a = ((const float4*)(xr + s * 32))[0];
                float4 b = ((const float4*)(xr + s * 32))[1];
                v[0] = a.x; v[1] = a.y; v[2] = a.z; v[3] = a.w;
                v[4] = b.x; v[5] = b.y; v[6] = b.z; v[7] = b.w;
            } else {
                uint4 raw = *(const uint4*)(xr + s * 32);
                const __half2* hp = (const __half2*)&raw;
#pragma unroll
                for (int k = 0; k < 4; ++k) {
                    float2 f = __half22float2(hp[k]);
                    v[2 * k] = f.x; v[2 * k + 1] = f.y;
                }
            }
#pragma unroll
            for (int j = 0; j < 8; ++j) {
                unsigned short h = f2bf_rne(v[j]);
                Ahi[r][s][j] = (short)h;
                float res = v[j] - __uint_as_float(((unsigned)h) << 16);
                Alo[r][s][j] = (short)f2bf_rne(res);
            }
        }
    }

    __syncthreads();

    floatx4 acc[2][8];
#pragma unroll
    for (int r = 0; r < 2; ++r)
#pragma unroll
        for (int t = 0; t < 8; ++t) acc[r][t] = (floatx4){0.f, 0.f, 0.f, 0.f};

    const short8* WH = (const short8*)WhiS;
    const short8* WL = (const short8*)WloS;
#pragma unroll
    for (int s = 0; s < 4; ++s) {
#pragma unroll
        for (int t = 0; t < 8; ++t) {
            short8 bh = WH[(t * 4 + s) * 64 + lane];
            short8 bl = WL[(t * 4 + s) * 64 + lane];
#pragma unroll
            for (int r = 0; r < 2; ++r) {
                acc[r][t] = __builtin_amdgcn_mfma_f32_16x16x32_bf16(Ahi[r][s], bh, acc[r][t], 0, 0, 0);
                acc[r][t] = __builtin_amdgcn_mfma_f32_16x16x32_bf16(Alo[r][s], bh, acc[r][t], 0, 0, 0);
                acc[r][t] = __builtin_amdgcn_mfma_f32_16x16x32_bf16(Ahi[r][s], bl, acc[r][t], 0, 0, 0);
            }
        }
    }

    float bcol[8];
    if (BIAS) {
#pragma unroll
        for (int t = 0; t < 8; ++t) bcol[t] = bias[t * 16 + l16];
    }
#pragma unroll
    for (int r = 0; r < 2; ++r) {
#pragma unroll
        for (int e = 0; e < 4; ++e) {
            int row = m0 + r * 16 + quad * 4 + e;
            if (row < M) {
                float sc = SCALE ? scale[row] : 1.f;
                OutT* yr = Y + (size_t)row * 128 + l16;
#pragma unroll
                for (int t = 0; t < 8; ++t) {
                    float v = acc[r][t][e];
                    if (SCALE) v *= sc;
                    if (BIAS) v += bcol[t];
                    if (RELU) v = fmaxf(v, 0.f);
                    if constexpr (sizeof(OutT) == 4) yr[t * 16] = v;
                    else yr[t * 16] = __float2half(v);
                }
            }
        }
    }
}

template <typename InT, typename OutT, bool SCALE, bool BIAS, bool RELU>
__global__ __launch_bounds__(256) void gemm_k(const InT* __restrict__ X,
                                              const short* __restrict__ Whi,
                                              const short* __restrict__ Wlo,
                                              const float* __restrict__ scale,
                                              const float* __restrict__ bias,
                                              OutT* __restrict__ Y, int M) {
    gemm_core<InT, OutT, SCALE, BIAS, RELU>(X, Whi, Wlo, scale, bias, Y, M, blockIdx.x);
}

__global__ __launch_bounds__(256) void gemm_heads_k(const float* __restrict__ X,
                                                    const short* __restrict__ WhiV,
                                                    const short* __restrict__ WloV,
                                                    const short* __restrict__ WhiT,
                                                    const short* __restrict__ WloT,
                                                    const float* __restrict__ bv,
                                                    const float* __restrict__ bt,
                                                    float* __restrict__ Yv,
                                                    float* __restrict__ Yt,
                                                    int M, int gb) {
    bool second = blockIdx.x >= gb;
    const short* hi = second ? WhiT : WhiV;
    const short* lo = second ? WloT : WloV;
    const float* b  = second ? bt : bv;
    float* Y        = second ? Yt : Yv;
    int blk         = second ? (blockIdx.x - gb) : blockIdx.x;
    gemm_core<float, float, false, true, true>(X, hi, lo, nullptr, b, Y, M, blk);
}

// ----------------------------- Aggregate ------------------------------------
// out[i] = op( dinv[i]*(hs[i] + sum_nb hs[col]) + b ), hs fp16, col_idx ushort.
// One node per 16-lane GROUP (4 nodes/wave, 16/block): 4x independent
// latency chains per wave, no cross-lane reduce, predicated gathers (no
// masked self-row loads). Each group reads full 256B rows (16 lanes x uint4).
template <bool RELU, typename OutT>
__global__ __launch_bounds__(256) void agg_k(const __half* __restrict__ hs,
                                             const int* __restrict__ row_ptr,
                                             const unsigned short* __restrict__ col_idx,
                                             const float* __restrict__ dinv,
                                             const float* __restrict__ bias,
                                             OutT* __restrict__ out, int n) {
    const int c = threadIdx.x & 15;           // column slice within group
    const int gbase = threadIdx.x & 48;       // group base lane within wave
    int grp = blockIdx.x * 16 + (threadIdx.x >> 4);
    int ngrp = gridDim.x * 16;

    float4 b0 = ((const float4*)bias)[c * 2];
    float4 b1 = ((const float4*)bias)[c * 2 + 1];

    for (int i = grp; i < n; i += ngrp) {
        float acc[8];
        {
            uint4 raw = ((const uint4*)(hs + (size_t)i * DFEAT))[c];
            const __half2* hp = (const __half2*)&raw;
#pragma unroll
            for (int k = 0; k < 4; ++k) {
                float2 f = __half22float2(hp[k]);
                acc[2 * k] = f.x; acc[2 * k + 1] = f.y;
            }
        }
        int s = row_ptr[i];
        int cnt = row_ptr[i + 1] - s;

        for (int base = 0; base < cnt; base += 16) {
            int t = base + c;
            int idx = (t < cnt) ? (int)col_idx[s + t] : 0;
            int lim = cnt - base; if (lim > 16) lim = 16;
            uint4 vv[16];
#pragma unroll
            for (int q = 0; q < 16; ++q) {
                int ia = __shfl(idx, gbase + q);
                if (q < lim)
                    vv[q] = ((const uint4*)(hs + (size_t)ia * DFEAT))[c];
            }
#pragma unroll
            for (int q = 0; q < 16; ++q) {
                if (q < lim) {
                    const __half2* pq = (const __half2*)&vv[q];
#pragma unroll
                    for (int k = 0; k < 4; ++k) {
                        float2 f = __half22float2(pq[k]);
                        acc[2 * k]     += f.x;
                        acc[2 * k + 1] += f.y;
                    }
                }
            }
        }

        float di = dinv[i];
        float o[8];
        o[0] = fmaf(acc[0], di, b0.x); o[1] = fmaf(acc[1], di, b0.y);
        o[2] = fmaf(acc[2], di, b0.z); o[3] = fmaf(acc[3], di, b0.w);
        o[4] = fmaf(acc[4], di, b1.x); o[5] = fmaf(acc[5], di, b1.y);
        o[6] = fmaf(acc[6], di, b1.z); o[7] = fmaf(acc[7], di, b1.w);
        if (RELU) {
#pragma unroll
            for (int k = 0; k < 8; ++k) o[k] = fmaxf(o[k], 0.f);
        }
        if constexpr (sizeof(OutT) == 4) {
            ((float4*)((float*)out + (size_t)i * DFEAT))[c * 2] =
                make_float4(o[0], o[1], o[2], o[3]);
            ((float4*)((float*)out + (size_t)i * DFEAT))[c * 2 + 1] =
                make_float4(o[4], o[5], o[6], o[7]);
        } else {
            __half2 hpk[4];
#pragma unroll
            for (int k = 0; k < 4; ++k)
                hpk[k] = __floats2half2_rn(o[2 * k], o[2 * k + 1]);
            ((uint4*)((__half*)out + (size_t)i * DFEAT))[c] = *(uint4*)hpk;
        }
    }
}

// ---------------------------------------------------------------------------

static inline size_t align_up(size_t x, size_t a) { return (x + a - 1) & ~(a - 1); }

extern "C" void kernel_launch(void* const* d_in, const int* in_sizes, int n_in,
                              void* d_out, int out_size, void* d_ws, size_t ws_size,
                              hipStream_t stream) {
    const float* x  = (const float*)d_in[0];
    const int*   ei = (const int*)d_in[1];
    const float* W0 = (const float*)d_in[2];
    const float* b0 = (const float*)d_in[3];
    const float* W1 = (const float*)d_in[4];
    const float* b1 = (const float*)d_in[5];
    const float* Wv = (const float*)d_in[6];
    const float* bv = (const float*)d_in[7];
    const float* Wt = (const float*)d_in[8];
    const float* bt = (const float*)d_in[9];

    const int N = in_sizes[0] / DFEAT;
    const int E = in_sizes[1] / 2;
    const int* src = ei;
    const int* dst = ei + E;
    const int nbuk = (N + 255) >> BSH;

    // workspace carve-up
    char* w = (char*)d_ws;
    int* bucket_cnt = (int*)w;  w += align_up((size_t)(nbuk + 1) * 4, 256);
    int* bucket_off = (int*)w;  w += align_up((size_t)(nbuk + 1) * 4, 256);
    int* bucket_cur = (int*)w;  w += align_up((size_t)nbuk * 4, 256);
    unsigned* pk_arr = (unsigned*)w; w += align_up((size_t)E * 4, 256);
    int* row_ptr    = (int*)w;  w += align_up((size_t)(N + 1) * 4, 256);
    unsigned short* col_idx = (unsigned short*)w; w += align_up((size_t)E * 2, 256);
    float* dinv     = (float*)w; w += align_up((size_t)N * 4, 256);
    short* whi_all  = (short*)w; w += align_up(4 * 16384 * 2, 256);
    short* wlo_all  = (short*)w; w += align_up(4 * 16384 * 2, 256);
    __half* hs      = (__half*)w; w += align_up((size_t)N * DFEAT * 2, 256);
    __half* h1      = (__half*)w; w += align_up((size_t)N * DFEAT * 2, 256);

    short* w0hi = whi_all;            short* w0lo = wlo_all;
    short* w1hi = whi_all + 16384;    short* w1lo = wlo_all + 16384;
    short* wvhi = whi_all + 2*16384;  short* wvlo = wlo_all + 2*16384;
    short* wthi = whi_all + 3*16384;  short* wtlo = wlo_all + 3*16384;

    float* out_h = (float*)d_out;
    float* out_v = out_h + (size_t)N * DFEAT;
    float* out_t = out_h + 2 * (size_t)N * DFEAT;

    const int gb = (N + 127) / 128;
    const int agg_blocks = (N + 15) / 16;   // one node per 16-lane group
    const int pb = (E + BKE - 1) / BKE;     // partition blocks (391)

    // CSR build (counting sort) + weight pre-split
    hipMemsetAsync(bucket_cnt, 0, (size_t)(nbuk + 1) * 4, stream);
    bucket_hist_k<<<256, 256, 0, stream>>>(dst, bucket_cnt, E, nbuk);
    prep_w4_k<<<256, 256, 0, stream>>>(W0, W1, Wv, Wt, whi_all, wlo_all);
    scan_buckets_k<<<1, 256, 0, stream>>>(bucket_cnt, bucket_off, bucket_cur, nbuk, E);
    partition_k<<<pb, 256, 0, stream>>>(src, dst, bucket_cur, pk_arr, E, nbuk);
    build_csr_k<<<nbuk, 256, 0, stream>>>(pk_arr, bucket_off, row_ptr, col_idx, dinv, N, E);

    // layer 0: hs = fp16( dinv * (x @ W0) )
    gemm_k<float, __half, true, false, false><<<gb, 256, 0, stream>>>(x, w0hi, w0lo, dinv, nullptr, hs, N);
    // h1 = fp16( relu(dinv * agg(hs) + b0) )
    agg_k<true, __half><<<agg_blocks, 256, 0, stream>>>(hs, row_ptr, col_idx, dinv, b0, h1, N);
    // layer 1: hs = fp16( dinv * (h1 @ W1) )
    gemm_k<__half, __half, true, false, false><<<gb, 256, 0, stream>>>(h1, w1hi, w1lo, dinv, nullptr, hs, N);
    // h = dinv * agg(hs) + b1 -> d_out (fp32)
    agg_k<false, float><<<agg_blocks, 256, 0, stream>>>(hs, row_ptr, col_idx, dinv, b1, out_h, N);
    // heads (fused dispatch)
    gemm_heads_k<<<2 * gb, 256, 0, stream>>>(out_h, wvhi, wvlo, wthi, wtlo, bv, bt, out_v, out_t, N, gb);
}

// Round 2
// 255.894 us; speedup vs baseline: 1.0839x; 1.0839x over previous
//
#include <hip/hip_runtime.h>
#include <hip/hip_fp16.h>
#include <math.h>

// ---------------------------------------------------------------------------
// GCN 2-layer + two heads, fp32 in/out, MI355X.
//   R7: dispatch consolidation 11 -> 7.
//   - hist writes per-block partials (no memset, no global atomics) + prep_w4
//     fused into the same dispatch.
//   - partition/build recompute the 196-bucket scan per-block from partials
//     (scan kernel eliminated).
//   - normalization re-associated: gemm0 unscaled, agg0 gathers dinv[col] as
//     edge weight and pre-scales its output by dinv -> gemm1/agg1 unchanged,
//     and build_csr + gemm0 fuse into ONE dispatch (latency-bound CSR blocks
//     co-resident with MFMA blocks).
// ---------------------------------------------------------------------------

#define DFEAT 128
#define BSH 8            // bucket = dst >> 8 (256 nodes/bucket)
#define BKE 4096         // edges per partition block (runs of ~21 -> coalesced)

using short8  = __attribute__((ext_vector_type(8))) short;
using floatx4 = __attribute__((ext_vector_type(4))) float;

__device__ __forceinline__ unsigned short f2bf_rne(float x) {
    unsigned u = __float_as_uint(x);
    unsigned r = u + 0x7FFFu + ((u >> 16) & 1u);
    return (unsigned short)(r >> 16);
}

// ---------------- K1: bucket partial histograms + W pre-split ---------------
// blocks 0..255: per-block bucket histogram -> part[bucket*256 + blk]
// (block 0 also zeroes the partition cursor)
// blocks 256..511: prep of the 4 weight matrices into MFMA hi/lo fragments.
__global__ __launch_bounds__(256) void histprep_k(const int* __restrict__ dst,
                                                  int* __restrict__ part,
                                                  int* __restrict__ cursor,
                                                  const float* __restrict__ W0,
                                                  const float* __restrict__ W1,
                                                  const float* __restrict__ W2,
                                                  const float* __restrict__ W3,
                                                  short* __restrict__ hi_all,
                                                  short* __restrict__ lo_all,
                                                  int E) {
    int tid = threadIdx.x;
    if (blockIdx.x < 256) {
        __shared__ int h[256];
        h[tid] = 0;
        if (blockIdx.x == 0) cursor[tid] = 0;
        __syncthreads();
        const int nb = 256;
        int len = ((E + nb - 1) / nb + 3) & ~3;
        int e0 = blockIdx.x * len;
        int e1 = E < e0 + len ? E : e0 + len;
        int m = e1 - e0; if (m < 0) m = 0;
        int e1a = e0 + (m & ~3);
        for (int e = e0 + tid * 4; e < e1a; e += 1024) {
            int4 d4 = *(const int4*)(dst + e);
            atomicAdd(&h[d4.x >> BSH], 1);
            atomicAdd(&h[d4.y >> BSH], 1);
            atomicAdd(&h[d4.z >> BSH], 1);
            atomicAdd(&h[d4.w >> BSH], 1);
        }
        for (int e = e1a + tid; e < e1; e += 256) atomicAdd(&h[dst[e] >> BSH], 1);
        __syncthreads();
        part[tid * 256 + blockIdx.x] = h[tid];
    } else {
        int pb = blockIdx.x - 256;
        int b = pb >> 6;
        const float* W = (b == 0) ? W0 : (b == 1) ? W1 : (b == 2) ? W2 : W3;
        short* hi = hi_all + (size_t)b * 16384;
        short* lo = lo_all + (size_t)b * 16384;
        int i = (pb & 63) * 256 + tid;
        int j = i & 7;
        int lane = (i >> 3) & 63;
        int ts = i >> 9;
        int s = ts & 3, t = ts >> 2;
        int k = s * 32 + (lane >> 4) * 8 + j;
        int n = t * 16 + (lane & 15);
        float x = W[k * 128 + n];
        unsigned short h = f2bf_rne(x);
        float res = x - __uint_as_float(((unsigned)h) << 16);
        hi[i] = (short)h;
        lo[i] = (short)f2bf_rne(res);
    }
}

// ---------------- K2: partition edges into buckets --------------------------
// Per-block redundant bucket scan from partials (no scan kernel, no
// pre-initialized cursor offsets). LDS rank atomics + one zero-based global
// reservation atomic per (block,bucket). Writes packed (dst<<16|src).
__global__ __launch_bounds__(256) void partition_k(const int* __restrict__ src,
                                                   const int* __restrict__ dst,
                                                   const int* __restrict__ part,
                                                   int* __restrict__ cursor,
                                                   unsigned* __restrict__ pk_out,
                                                   int E, int nbuk) {
    __shared__ int h[256];
    __shared__ int base[256];
    __shared__ int sx[256];
    int tid = threadIdx.x;

    // bucket totals + exclusive scan (redundant per block; partials L2-hit)
    int v = 0;
    if (tid < nbuk) {
        const int4* pr = (const int4*)(part + (size_t)tid * 256);
#pragma unroll 8
        for (int q = 0; q < 64; ++q) { int4 t4 = pr[q]; v += t4.x + t4.y + t4.z + t4.w; }
    }
    sx[tid] = v;
    __syncthreads();
    int x = v;
    for (int o = 1; o < 256; o <<= 1) {
        int y = (tid >= o) ? sx[tid - o] : 0;
        __syncthreads();
        x += y;
        sx[tid] = x;
        __syncthreads();
    }
    int offx = x - v;     // global base of bucket `tid`

    h[tid] = 0;
    __syncthreads();

    int e0 = blockIdx.x * BKE;
    unsigned pk[16];
    unsigned short rk[16];
    unsigned char bk[16];
    int m = 0;
#pragma unroll
    for (int it = 0; it < 4; ++it) {
        int e = e0 + it * 1024 + tid * 4;
        if (e + 3 < E) {
            int4 d4 = *(const int4*)(dst + e);
            int4 s4 = *(const int4*)(src + e);
            int dd[4] = {d4.x, d4.y, d4.z, d4.w};
            int ss[4] = {s4.x, s4.y, s4.z, s4.w};
#pragma unroll
            for (int k = 0; k < 4; ++k) {
                int b = dd[k] >> BSH;
                pk[m] = ((unsigned)dd[k] << 16) | (unsigned)ss[k];
                rk[m] = (unsigned short)atomicAdd(&h[b], 1);
                bk[m] = (unsigned char)b;
                ++m;
            }
        } else {
            for (int k = 0; k < 4; ++k) {
                if (e + k < E) {
                    int d = dst[e + k], sv = src[e + k];
                    int b = d >> BSH;
                    pk[m] = ((unsigned)d << 16) | (unsigned)sv;
                    rk[m] = (unsigned short)atomicAdd(&h[b], 1);
                    bk[m] = (unsigned char)b;
                    ++m;
                }
            }
        }
    }
    __syncthreads();
    if (tid < nbuk && h[tid]) base[tid] = offx + atomicAdd(&cursor[tid], h[tid]);
    __syncthreads();
    for (int j = 0; j < m; ++j)
        pk_out[base[bk[j]] + (int)rk[j]] = pk[j];
}

// ----------------------- GEMM via split-bf16 MFMA ---------------------------
template <typename InT, typename OutT, bool BIAS, bool RELU>
__device__ __forceinline__ void gemm_core(const InT* __restrict__ X,
                                          const short* __restrict__ Whi,
                                          const short* __restrict__ Wlo,
                                          const float* __restrict__ bias,
                                          OutT* __restrict__ Y, int M, int blk) {
    __shared__ short WhiS[16384];
    __shared__ short WloS[16384];
    const int tid = threadIdx.x;

#pragma unroll
    for (int j = 0; j < 8; ++j)
        ((float4*)WhiS)[tid + j * 256] = ((const float4*)Whi)[tid + j * 256];
#pragma unroll
    for (int j = 0; j < 8; ++j)
        ((float4*)WloS)[tid + j * 256] = ((const float4*)Wlo)[tid + j * 256];

    const int wave = tid >> 6, lane = tid & 63;
    const int quad = lane >> 4, l16 = lane & 15;
    const int m0 = blk * 128 + wave * 32;

    short8 Ahi[2][4], Alo[2][4];
#pragma unroll
    for (int r = 0; r < 2; ++r) {
        int row = m0 + r * 16 + l16;
        row = row < M ? row : (M - 1);
        const InT* xr = X + (size_t)row * 128 + quad * 8;
#pragma unroll
        for (int s = 0; s < 4; ++s) {
            float v[8];
            if constexpr (sizeof(InT) == 4) {
                float4 a = ((const float4*)(xr + s * 32))[0];
                float4 b = ((const float4*)(xr + s * 32))[1];
                v[0] = a.x; v[1] = a.y; v[2] = a.z; v[3] = a.w;
                v[4] = b.x; v[5] = b.y; v[6] = b.z; v[7] = b.w;
            } else {
                uint4 raw = *(const uint4*)(xr + s * 32);
                const __half2* hp = (const __half2*)&raw;
#pragma unroll
                for (int k = 0; k < 4; ++k) {
                    float2 f = __half22float2(hp[k]);
                    v[2 * k] = f.x; v[2 * k + 1] = f.y;
                }
            }
#pragma unroll
            for (int j = 0; j < 8; ++j) {
                unsigned short h = f2bf_rne(v[j]);
                Ahi[r][s][j] = (short)h;
                float res = v[j] - __uint_as_float(((unsigned)h) << 16);
                Alo[r][s][j] = (short)f2bf_rne(res);
            }
        }
    }

    __syncthreads();

    floatx4 acc[2][8];
#pragma unroll
    for (int r = 0; r < 2; ++r)
#pragma unroll
        for (int t = 0; t < 8; ++t) acc[r][t] = (floatx4){0.f, 0.f, 0.f, 0.f};

    const short8* WH = (const short8*)WhiS;
    const short8* WL = (const short8*)WloS;
#pragma unroll
    for (int s = 0; s < 4; ++s) {
#pragma unroll
        for (int t = 0; t < 8; ++t) {
            short8 bh = WH[(t * 4 + s) * 64 + lane];
            short8 bl = WL[(t * 4 + s) * 64 + lane];
#pragma unroll
            for (int r = 0; r < 2; ++r) {
                acc[r][t] = __builtin_amdgcn_mfma_f32_16x16x32_bf16(Ahi[r][s], bh, acc[r][t], 0, 0, 0);
                acc[r][t] = __builtin_amdgcn_mfma_f32_16x16x32_bf16(Alo[r][s], bh, acc[r][t], 0, 0, 0);
                acc[r][t] = __builtin_amdgcn_mfma_f32_16x16x32_bf16(Ahi[r][s], bl, acc[r][t], 0, 0, 0);
            }
        }
    }

    float bcol[8];
    if (BIAS) {
#pragma unroll
        for (int t = 0; t < 8; ++t) bcol[t] = bias[t * 16 + l16];
    }
#pragma unroll
    for (int r = 0; r < 2; ++r) {
#pragma unroll
        for (int e = 0; e < 4; ++e) {
            int row = m0 + r * 16 + quad * 4 + e;
            if (row < M) {
                OutT* yr = Y + (size_t)row * 128 + l16;
#pragma unroll
                for (int t = 0; t < 8; ++t) {
                    float v = acc[r][t][e];
                    if (BIAS) v += bcol[t];
                    if (RELU) v = fmaxf(v, 0.f);
                    if constexpr (sizeof(OutT) == 4) yr[t * 16] = v;
                    else yr[t * 16] = __float2half(v);
                }
            }
        }
    }
}

template <typename InT, typename OutT, bool BIAS, bool RELU>
__global__ __launch_bounds__(256) void gemm_k(const InT* __restrict__ X,
                                              const short* __restrict__ Whi,
                                              const short* __restrict__ Wlo,
                                              const float* __restrict__ bias,
                                              OutT* __restrict__ Y, int M) {
    gemm_core<InT, OutT, BIAS, RELU>(X, Whi, Wlo, bias, Y, M, blockIdx.x);
}

// ---------------- K3: fused CSR build + layer-0 GEMM ------------------------
// blocks [0, nbuk): per-bucket exact CSR (per-block redundant scan -> slab
// offsets). blocks [nbuk, nbuk+gb): unscaled x@W0 -> fp16. The CSR blocks are
// latency-bound, the GEMM blocks MFMA-bound -> good co-residency.
__global__ __launch_bounds__(256) void csrgemm_k(const unsigned* __restrict__ pk_arr,
                                                 const int* __restrict__ part,
                                                 int* __restrict__ row_ptr,
                                                 unsigned short* __restrict__ col_idx,
                                                 float* __restrict__ dinv,
                                                 const float* __restrict__ X,
                                                 const short* __restrict__ Whi,
                                                 const short* __restrict__ Wlo,
                                                 __half* __restrict__ Y,
                                                 int N, int E, int nbuk) {
    if ((int)blockIdx.x >= nbuk) {
        gemm_core<float, __half, false, false>(X, Whi, Wlo, nullptr, Y, N, blockIdx.x - nbuk);
        return;
    }
    __shared__ int hcnt[256];
    __shared__ int esc[256];
    __shared__ int sx[256];
    int b = blockIdx.x, tid = threadIdx.x;

    // slab offsets via redundant scan of partials
    int v = 0;
    if (tid < nbuk) {
        const int4* pr = (const int4*)(part + (size_t)tid * 256);
#pragma unroll 8
        for (int q = 0; q < 64; ++q) { int4 t4 = pr[q]; v += t4.x + t4.y + t4.z + t4.w; }
    }
    sx[tid] = v;
    __syncthreads();
    int x = v;
    for (int o = 1; o < 256; o <<= 1) {
        int y = (tid >= o) ? sx[tid - o] : 0;
        __syncthreads();
        x += y;
        sx[tid] = x;
        __syncthreads();
    }
    int s0 = (b > 0) ? sx[b - 1] : 0;
    int cnt = sx[b] - s0;
    __syncthreads();

    hcnt[tid] = 0;
    __syncthreads();

    unsigned p[20];
    unsigned short r[20];
    int m = 0;
    for (int i = tid; i < cnt; i += 256) {
        unsigned pp = pk_arr[s0 + i];
        int d = (pp >> 16) & 255;
        r[m] = (unsigned short)atomicAdd(&hcnt[d], 1);
        p[m] = pp;
        ++m;
    }
    __syncthreads();

    int hv = hcnt[tid];
    esc[tid] = hv;
    __syncthreads();
    int hx = hv;
    for (int o = 1; o < 256; o <<= 1) {
        int y = (tid >= o) ? esc[tid - o] : 0;
        __syncthreads();
        hx += y;
        esc[tid] = hx;
        __syncthreads();
    }
    int excl = hx - hv;
    __syncthreads();
    esc[tid] = excl;
    __syncthreads();

    int node = (b << BSH) + tid;
    if (node < N) {
        row_ptr[node] = s0 + excl;
        dinv[node] = rsqrtf((float)(hv + 1));   // +1 self loop
    }
    if (node == N) row_ptr[N] = E;

    for (int j = 0; j < m; ++j) {
        int d = (p[j] >> 16) & 255;
        col_idx[s0 + esc[d] + (int)r[j]] = (unsigned short)(p[j] & 0xFFFFu);
    }
}

// ---------------- K4: layer-0 aggregate (dinv-weighted gather) --------------
// h0 table is UNSCALED; edge weight dinv[col] is gathered (4B/edge extra).
// out = dinv_i * relu(dinv_i * acc + b0)  (pre-scaled so layer-1 GEMM needs
// no dinv). One node per 16-lane group.
__global__ __launch_bounds__(256) void agg0_k(const __half* __restrict__ hs,
                                              const int* __restrict__ row_ptr,
                                              const unsigned short* __restrict__ col_idx,
                                              const float* __restrict__ dinv,
                                              const float* __restrict__ bias,
                                              __half* __restrict__ out, int n) {
    const int c = threadIdx.x & 15;
    const int gbase = threadIdx.x & 48;
    int grp = blockIdx.x * 16 + (threadIdx.x >> 4);
    int ngrp = gridDim.x * 16;

    float4 b0 = ((const float4*)bias)[c * 2];
    float4 b1 = ((const float4*)bias)[c * 2 + 1];

    for (int i = grp; i < n; i += ngrp) {
        float di = dinv[i];
        float acc[8];
        {
            uint4 raw = ((const uint4*)(hs + (size_t)i * DFEAT))[c];
            const __half2* hp = (const __half2*)&raw;
#pragma unroll
            for (int k = 0; k < 4; ++k) {
                float2 f = __half22float2(hp[k]);
                acc[2 * k] = f.x * di; acc[2 * k + 1] = f.y * di;
            }
        }
        int s = row_ptr[i];
        int cnt = row_ptr[i + 1] - s;

        for (int base = 0; base < cnt; base += 16) {
            int t = base + c;
            int idx = (t < cnt) ? (int)col_idx[s + t] : 0;
            float dv = (t < cnt) ? dinv[idx] : 0.f;
            int lim = cnt - base; if (lim > 16) lim = 16;
            uint4 vv[16];
#pragma unroll
            for (int q = 0; q < 16; ++q) {
                int ia = __shfl(idx, gbase + q);
                if (q < lim)
                    vv[q] = ((const uint4*)(hs + (size_t)ia * DFEAT))[c];
            }
            float w[16];
#pragma unroll
            for (int q = 0; q < 16; ++q) w[q] = __shfl(dv, gbase + q);
#pragma unroll
            for (int q = 0; q < 16; ++q) {
                if (q < lim) {
                    const __half2* pq = (const __half2*)&vv[q];
#pragma unroll
                    for (int k = 0; k < 4; ++k) {
                        float2 f = __half22float2(pq[k]);
                        acc[2 * k]     = fmaf(f.x, w[q], acc[2 * k]);
                        acc[2 * k + 1] = fmaf(f.y, w[q], acc[2 * k + 1]);
                    }
                }
            }
        }

        float o[8];
        o[0] = fmaf(acc[0], di, b0.x); o[1] = fmaf(acc[1], di, b0.y);
        o[2] = fmaf(acc[2], di, b0.z); o[3] = fmaf(acc[3], di, b0.w);
        o[4] = fmaf(acc[4], di, b1.x); o[5] = fmaf(acc[5], di, b1.y);
        o[6] = fmaf(acc[6], di, b1.z); o[7] = fmaf(acc[7], di, b1.w);
#pragma unroll
        for (int k = 0; k < 8; ++k) o[k] = fmaxf(o[k], 0.f) * di;  // h1' = di*relu

        __half2 hpk[4];
#pragma unroll
        for (int k = 0; k < 4; ++k)
            hpk[k] = __floats2half2_rn(o[2 * k], o[2 * k + 1]);
        ((uint4*)((__half*)out + (size_t)i * DFEAT))[c] = *(uint4*)hpk;
    }
}

// ---------------- K6: layer-1 aggregate (unweighted; table pre-scaled) ------
__global__ __launch_bounds__(256) void agg1_k(const __half* __restrict__ hs,
                                              const int* __restrict__ row_ptr,
                                              const unsigned short* __restrict__ col_idx,
                                              const float* __restrict__ dinv,
                                              const float* __restrict__ bias,
                                              float* __restrict__ out, int n) {
    const int c = threadIdx.x & 15;
    const int gbase = threadIdx.x & 48;
    int grp = blockIdx.x * 16 + (threadIdx.x >> 4);
    int ngrp = gridDim.x * 16;

    float4 b0 = ((const float4*)bias)[c * 2];
    float4 b1 = ((const float4*)bias)[c * 2 + 1];

    for (int i = grp; i < n; i += ngrp) {
        float acc[8];
        {
            uint4 raw = ((const uint4*)(hs + (size_t)i * DFEAT))[c];
            const __half2* hp = (const __half2*)&raw;
#pragma unroll
            for (int k = 0; k < 4; ++k) {
                float2 f = __half22float2(hp[k]);
                acc[2 * k] = f.x; acc[2 * k + 1] = f.y;
            }
        }
        int s = row_ptr[i];
        int cnt = row_ptr[i + 1] - s;

        for (int base = 0; base < cnt; base += 16) {
            int t = base + c;
            int idx = (t < cnt) ? (int)col_idx[s + t] : 0;
            int lim = cnt - base; if (lim > 16) lim = 16;
            uint4 vv[16];
#pragma unroll
            for (int q = 0; q < 16; ++q) {
                int ia = __shfl(idx, gbase + q);
                if (q < lim)
                    vv[q] = ((const uint4*)(hs + (size_t)ia * DFEAT))[c];
            }
#pragma unroll
            for (int q = 0; q < 16; ++q) {
                if (q < lim) {
                    const __half2* pq = (const __half2*)&vv[q];
#pragma unroll
                    for (int k = 0; k < 4; ++k) {
                        float2 f = __half22float2(pq[k]);
                        acc[2 * k]     += f.x;
                        acc[2 * k + 1] += f.y;
                    }
                }
            }
        }

        float di = dinv[i];
        float o[8];
        o[0] = fmaf(acc[0], di, b0.x); o[1] = fmaf(acc[1], di, b0.y);
        o[2] = fmaf(acc[2], di, b0.z); o[3] = fmaf(acc[3], di, b0.w);
        o[4] = fmaf(acc[4], di, b1.x); o[5] = fmaf(acc[5], di, b1.y);
        o[6] = fmaf(acc[6], di, b1.z); o[7] = fmaf(acc[7], di, b1.w);
        ((float4*)(out + (size_t)i * DFEAT))[c * 2] =
            make_float4(o[0], o[1], o[2], o[3]);
        ((float4*)(out + (size_t)i * DFEAT))[c * 2 + 1] =
            make_float4(o[4], o[5], o[6], o[7]);
    }
}

// ---------------- K7: heads (fused dispatch) --------------------------------
__global__ __launch_bounds__(256) void gemm_heads_k(const float* __restrict__ X,
                                                    const short* __restrict__ WhiV,
                                                    const short* __restrict__ WloV,
                                                    const short* __restrict__ WhiT,
                                                    const short* __restrict__ WloT,
                                                    const float* __restrict__ bv,
                                                    const float* __restrict__ bt,
                                                    float* __restrict__ Yv,
                                                    float* __restrict__ Yt,
                                                    int M, int gb) {
    bool second = (int)blockIdx.x >= gb;
    const short* hi = second ? WhiT : WhiV;
    const short* lo = second ? WloT : WloV;
    const float* b  = second ? bt : bv;
    float* Y        = second ? Yt : Yv;
    int blk         = second ? (blockIdx.x - gb) : blockIdx.x;
    gemm_core<float, float, true, true>(X, hi, lo, b, Y, M, blk);
}

// ---------------------------------------------------------------------------

static inline size_t align_up(size_t x, size_t a) { return (x + a - 1) & ~(a - 1); }

extern "C" void kernel_launch(void* const* d_in, const int* in_sizes, int n_in,
                              void* d_out, int out_size, void* d_ws, size_t ws_size,
                              hipStream_t stream) {
    const float* x  = (const float*)d_in[0];
    const int*   ei = (const int*)d_in[1];
    const float* W0 = (const float*)d_in[2];
    const float* b0 = (const float*)d_in[3];
    const float* W1 = (const float*)d_in[4];
    const float* b1 = (const float*)d_in[5];
    const float* Wv = (const float*)d_in[6];
    const float* bv = (const float*)d_in[7];
    const float* Wt = (const float*)d_in[8];
    const float* bt = (const float*)d_in[9];

    const int N = in_sizes[0] / DFEAT;
    const int E = in_sizes[1] / 2;
    const int* src = ei;
    const int* dst = ei + E;
    const int nbuk = (N + 255) >> BSH;

    // workspace carve-up
    char* w = (char*)d_ws;
    int* part       = (int*)w;  w += align_up((size_t)256 * 256 * 4, 256);
    int* bucket_cur = (int*)w;  w += align_up((size_t)256 * 4, 256);
    unsigned* pk_arr = (unsigned*)w; w += align_up((size_t)E * 4, 256);
    int* row_ptr    = (int*)w;  w += align_up((size_t)(N + 1) * 4, 256);
    unsigned short* col_idx = (unsigned short*)w; w += align_up((size_t)E * 2, 256);
    float* dinv     = (float*)w; w += align_up((size_t)N * 4, 256);
    short* whi_all  = (short*)w; w += align_up(4 * 16384 * 2, 256);
    short* wlo_all  = (short*)w; w += align_up(4 * 16384 * 2, 256);
    __half* hs      = (__half*)w; w += align_up((size_t)N * DFEAT * 2, 256);
    __half* h1      = (__half*)w; w += align_up((size_t)N * DFEAT * 2, 256);

    short* w0hi = whi_all;            short* w0lo = wlo_all;
    short* w1hi = whi_all + 16384;    short* w1lo = wlo_all + 16384;
    short* wvhi = whi_all + 2*16384;  short* wvlo = wlo_all + 2*16384;
    short* wthi = whi_all + 3*16384;  short* wtlo = wlo_all + 3*16384;

    float* out_h = (float*)d_out;
    float* out_v = out_h + (size_t)N * DFEAT;
    float* out_t = out_h + 2 * (size_t)N * DFEAT;

    const int gb = (N + 127) / 128;
    const int agg_blocks = (N + 15) / 16;
    const int pb = (E + BKE - 1) / BKE;

    // K1: bucket partial hists + weight pre-split (no memset needed)
    histprep_k<<<512, 256, 0, stream>>>(dst, part, bucket_cur, W0, W1, Wv, Wt,
                                        whi_all, wlo_all, E);
    // K2: partition into buckets (per-block scan from partials)
    partition_k<<<pb, 256, 0, stream>>>(src, dst, part, bucket_cur, pk_arr, E, nbuk);
    // K3: CSR build + unscaled layer-0 GEMM (co-resident)
    csrgemm_k<<<nbuk + gb, 256, 0, stream>>>(pk_arr, part, row_ptr, col_idx, dinv,
                                             x, w0hi, w0lo, hs, N, E, nbuk);
    // K4: weighted aggregate -> h1' = dinv*relu(dinv*acc + b0), fp16
    agg0_k<<<agg_blocks, 256, 0, stream>>>(hs, row_ptr, col_idx, dinv, b0, h1, N);
    // K5: layer-1 GEMM (input pre-scaled -> output automatically scaled)
    gemm_k<__half, __half, false, false><<<gb, 256, 0, stream>>>(h1, w1hi, w1lo, nullptr, hs, N);
    // K6: plain aggregate -> out_h = dinv*acc + b1, fp32
    agg1_k<<<agg_blocks, 256, 0, stream>>>(hs, row_ptr, col_idx, dinv, b1, out_h, N);
    // K7: heads
    gemm_heads_k<<<2 * gb, 256, 0, stream>>>(out_h, wvhi, wvlo, wthi, wtlo, bv, bt,
                                             out_v, out_t, N, gb);
}